// Round 7
// baseline (1052.616 us; speedup 1.0000x reference)
//
#include <hip/hip_runtime.h>
#include <math.h>

#define NN   50000
#define NE   800000
#define ESL  (NE + NN)     // CSR slots incl. one self-loop per node
#define DIN1 128
#define DE   16
#define C    64
#define HID  256
#define DCLS 144
#define KP   160      // DCLS padded to multiple of 32
#define LDA  168      // LDS row stride (bf16 elems), multiple of 8 for 16B align
#define NEGS 0.2f
#define NBLK ((NN + 255) / 256)   // 196 scan blocks

// fused kernel block ranges
#define SCAT_B ((NE + NN + 255) / 256)   // 3321
#define LIN1_B (NN / 16)                 // 3125 (16 nodes/block, 256 thr)
#define CVT_B  ((HID * KP) / 256)        // 160

typedef __attribute__((ext_vector_type(8))) short  short8;   // 8 bf16 in 4 VGPRs
typedef __attribute__((ext_vector_type(4))) float  f32x4;

// float -> bf16 (RNE)
__device__ __forceinline__ ushort f2bf(float f) {
    unsigned u = __float_as_uint(f);
    u += 0x7fffu + ((u >> 16) & 1u);
    return (ushort)(u >> 16);
}
__device__ __forceinline__ float bf2f(ushort u) {
    return __uint_as_float(((unsigned)u) << 16);
}
// packed bf16 pair -> two floats (1 op each)
__device__ __forceinline__ float bflo(unsigned w) { return __uint_as_float(w << 16); }
__device__ __forceinline__ float bfhi(unsigned w) { return __uint_as_float(w & 0xffff0000u); }

// ---- degree histogram ----
__global__ void k_deg(const int* __restrict__ dst, int* __restrict__ deg) {
    int e = blockIdx.x * blockDim.x + threadIdx.x;
    if (e < NE) atomicAdd(&deg[dst[e]], 1);
}

// ---- scan stage 1: block-local inclusive scan of (deg+1) ----
__global__ void k_scan1(const int* __restrict__ deg, int* __restrict__ rowptr,
                        int* __restrict__ bsum) {
    __shared__ int s[256];
    int t = threadIdx.x;
    int i = blockIdx.x * 256 + t;
    int v = (i < NN) ? (deg[i] + 1) : 0;
    s[t] = v;
    __syncthreads();
    for (int off = 1; off < 256; off <<= 1) {
        int u = (t >= off) ? s[t - off] : 0;
        __syncthreads();
        s[t] += u;
        __syncthreads();
    }
    if (i < NN) rowptr[i] = s[t] - v;          // exclusive within block
    if (t == 255) bsum[blockIdx.x] = s[255];
}

// ---- scan stages 2+3 merged: every block re-scans bsum, adds its prefix ----
__global__ void k_scan23(const int* __restrict__ bsum, int* __restrict__ rowptr) {
    __shared__ int s[256];
    int t = threadIdx.x;
    int v = (t < NBLK) ? bsum[t] : 0;
    s[t] = v;
    __syncthreads();
    for (int off = 1; off < 256; off <<= 1) {
        int u = (t >= off) ? s[t - off] : 0;
        __syncthreads();
        s[t] += u;
        __syncthreads();
    }
    int add = (blockIdx.x > 0) ? s[blockIdx.x - 1] : 0;
    int i = blockIdx.x * 256 + t;
    if (i < NN) rowptr[i] += add;
    if (i == 0) rowptr[NN] = ESL;
}

// ---- lin body: 256 threads cover 16 nodes (two 128-thread halves of 8) ----
template<int DINT>
__device__ __forceinline__ void lin_body(
        int lb, int t, const float* __restrict__ x,
        const float* __restrict__ Wl, const float* __restrict__ bl,
        const float* __restrict__ Wr, const float* __restrict__ br,
        ushort* __restrict__ xlb, float* __restrict__ xr) {
    int i0 = lb * 16 + (t >> 7) * 8;
    int tt = t & 127;
    int c = tt & 63;
    bool isl = tt < 64;
    const float* W = isl ? Wl : Wr;
    float bb = isl ? bl[c] : br[c];
    float acc[8];
#pragma unroll
    for (int n = 0; n < 8; ++n) acc[n] = bb;
    for (int k = 0; k < DINT; ++k) {
        float wk = W[k * C + c];
#pragma unroll
        for (int n = 0; n < 8; ++n)
            acc[n] = fmaf(x[(size_t)(i0 + n) * DINT + k], wk, acc[n]);
    }
    if (isl) {
#pragma unroll
        for (int n = 0; n < 8; ++n)
            xlb[(size_t)(i0 + n) * C + c] = f2bf(acc[n]);
    } else {
#pragma unroll
        for (int n = 0; n < 8; ++n)
            xr[(size_t)(i0 + n) * C + c] = acc[n];
    }
}

// ---- fused: scatter(+self slots) | lin1 | cvt_w  (independent parts) ----
__global__ void k_fused(const int* __restrict__ src, const int* __restrict__ dst,
                        const float* __restrict__ eattr,
                        const int* __restrict__ rowptr, int* __restrict__ cursor,
                        int* __restrict__ src_perm, ushort* __restrict__ eap,
                        const float* __restrict__ x,
                        const float* __restrict__ W1l, const float* __restrict__ b1l,
                        const float* __restrict__ W1r, const float* __restrict__ b1r,
                        ushort* __restrict__ xlb, float* __restrict__ xr,
                        const float* __restrict__ Cw1, short* __restrict__ Cw1T) {
    int b = blockIdx.x;
    int t = threadIdx.x;
    if (b < SCAT_B) {
        int e = b * 256 + t;
        if (e < NE) {
            int d = dst[e];
            int pos = atomicAdd(&cursor[d], 1);
            int idx = rowptr[d] + pos;
            src_perm[idx] = src[e];
            const float4* p4 = (const float4*)&eattr[(size_t)e * DE];
            float4 c0 = p4[0], c1 = p4[1], c2 = p4[2], c3 = p4[3];
            short8 r0, r1;
            r0[0]=f2bf(c0.x); r0[1]=f2bf(c0.y); r0[2]=f2bf(c0.z); r0[3]=f2bf(c0.w);
            r0[4]=f2bf(c1.x); r0[5]=f2bf(c1.y); r0[6]=f2bf(c1.z); r0[7]=f2bf(c1.w);
            r1[0]=f2bf(c2.x); r1[1]=f2bf(c2.y); r1[2]=f2bf(c2.z); r1[3]=f2bf(c2.w);
            r1[4]=f2bf(c3.x); r1[5]=f2bf(c3.y); r1[6]=f2bf(c3.z); r1[7]=f2bf(c3.w);
            short8* q = (short8*)&eap[(size_t)idx * DE];
            q[0] = r0; q[1] = r1;
        } else if (e < NE + NN) {
            int n = e - NE;
            src_perm[rowptr[n + 1] - 1] = n;   // self slot
        }
    } else if (b < SCAT_B + LIN1_B) {
        lin_body<DIN1>(b - SCAT_B, t, x, W1l, b1l, W1r, b1r, xlb, xr);
    } else {
        int idx = (b - SCAT_B - LIN1_B) * 256 + t;   // < 40960
        int n = idx / KP, k = idx - n * KP;
        Cw1T[n * KP + k] = (k < DCLS) ? (short)f2bf(Cw1[k * HID + n]) : (short)0;
    }
}

// ---- standalone lin (layer 2) ----
template<int DINT>
__global__ void k_lin(const float* __restrict__ x,
                      const float* __restrict__ Wl, const float* __restrict__ bl,
                      const float* __restrict__ Wr, const float* __restrict__ br,
                      ushort* __restrict__ xlb, float* __restrict__ xr) {
    lin_body<DINT>(blockIdx.x, threadIdx.x, x, Wl, bl, Wr, br, xlb, xr);
}

// ---- fused GAT layer, 4-edge x 16-lane layout, src prefetch ----
// SELF_INLINE=1: iterate real edges only, accumulate attr-mean on the fly,
// process self-loop inline, write mean into the CSR self slot for layer 2.
template<int DO_ELU, int OUT_BF16, int SELF_INLINE>
__global__ __launch_bounds__(64, 3) void k_gat(
        const int* __restrict__ src_perm, const int* __restrict__ rowptr,
        ushort* __restrict__ eap,
        const ushort* __restrict__ xlb, const float* __restrict__ xr,
        const float* __restrict__ We, const float* __restrict__ att,
        const float* __restrict__ bias, void* __restrict__ o_) {
    int d = blockIdx.x;
    int lane = threadIdx.x;
    int g = lane >> 4, l = lane & 15;
    int c0 = l * 4;
    float wreg[DE][4];
#pragma unroll
    for (int j = 0; j < DE; ++j) {
        float4 wv = *(const float4*)&We[j * C + c0];
        wreg[j][0] = wv.x; wreg[j][1] = wv.y; wreg[j][2] = wv.z; wreg[j][3] = wv.w;
    }
    float4 av4 = *(const float4*)&att[c0];
    float attv[4] = {av4.x, av4.y, av4.z, av4.w};
    float4 xr4 = *(const float4*)&xr[(size_t)d * C + c0];
    float xrv[4] = {xr4.x, xr4.y, xr4.z, xr4.w};

    float l_run = 0.f, n_run[4] = {0.f, 0.f, 0.f, 0.f};
    float easum[DE];
    if (SELF_INLINE) {
#pragma unroll
        for (int j = 0; j < DE; ++j) easum[j] = 0.f;
    }
    int kb = rowptr[d], ke = rowptr[d + 1];
    int kend = SELF_INLINE ? (ke - 1) : ke;

    if (kend > kb) {
        // prefetch first batch's src index
        int kk0 = kb + g;
        int s_cur = src_perm[(kk0 < kend) ? kk0 : kb];
        for (int k = kb; k < kend; k += 4) {
            int kk = k + g;
            bool valid = kk < kend;
            int kidx = valid ? kk : kb;
            // prefetch next batch's src (breaks the src->xl serial chain)
            int kkn = kk + 4;
            int s_nxt = src_perm[(kkn < kend) ? kkn : kb];
            float validf = valid ? 1.f : 0.f;
            uint2 xlr = *(const uint2*)&xlb[(size_t)s_cur * C + c0];
            float xlv[4] = {bflo(xlr.x), bfhi(xlr.x), bflo(xlr.y), bfhi(xlr.y)};
            const uint4* ep = (const uint4*)&eap[(size_t)kidx * DE];
            uint4 e0 = ep[0], e1 = ep[1];
            float m[4];
#pragma unroll
            for (int i = 0; i < 4; ++i) m[i] = xlv[i] + xrv[i];
            unsigned ew[8] = {e0.x, e0.y, e0.z, e0.w, e1.x, e1.y, e1.z, e1.w};
#pragma unroll
            for (int wji = 0; wji < 8; ++wji) {
                float elo = bflo(ew[wji]), ehi = bfhi(ew[wji]);
#pragma unroll
                for (int i = 0; i < 4; ++i) {
                    m[i] = fmaf(elo, wreg[2 * wji][i], m[i]);
                    m[i] = fmaf(ehi, wreg[2 * wji + 1][i], m[i]);
                }
                if (SELF_INLINE) {
                    easum[2 * wji]     = fmaf(validf, elo, easum[2 * wji]);
                    easum[2 * wji + 1] = fmaf(validf, ehi, easum[2 * wji + 1]);
                }
            }
            float p = 0.f;
#pragma unroll
            for (int i = 0; i < 4; ++i) {
                float tt = fmaxf(m[i], NEGS * m[i]);   // leaky_relu
                p = fmaf(tt, attv[i], p);
            }
            p += __shfl_xor(p, 1);
            p += __shfl_xor(p, 2);
            p += __shfl_xor(p, 4);
            p += __shfl_xor(p, 8);
            float pe = valid ? __expf(p) : 0.f;
            l_run += pe;
#pragma unroll
            for (int i = 0; i < 4; ++i) n_run[i] = fmaf(pe, xlv[i], n_run[i]);
            s_cur = s_nxt;
        }
    }

    if (SELF_INLINE) {
        // total attr sums across groups -> mean; write self slot; self-loop edge
#pragma unroll
        for (int j = 0; j < DE; ++j) {
            easum[j] += __shfl_xor(easum[j], 16);
            easum[j] += __shfl_xor(easum[j], 32);
        }
        float rdeg = 1.f / fmaxf((float)(kend - kb), 1.f);
        float mean[DE];
#pragma unroll
        for (int j = 0; j < DE; ++j) mean[j] = easum[j] * rdeg;
        if (lane == 0) {   // all lanes hold identical mean -> single-lane 32B store
            uint4 w0, w1;
            w0.x = (unsigned)f2bf(mean[0])  | ((unsigned)f2bf(mean[1])  << 16);
            w0.y = (unsigned)f2bf(mean[2])  | ((unsigned)f2bf(mean[3])  << 16);
            w0.z = (unsigned)f2bf(mean[4])  | ((unsigned)f2bf(mean[5])  << 16);
            w0.w = (unsigned)f2bf(mean[6])  | ((unsigned)f2bf(mean[7])  << 16);
            w1.x = (unsigned)f2bf(mean[8])  | ((unsigned)f2bf(mean[9])  << 16);
            w1.y = (unsigned)f2bf(mean[10]) | ((unsigned)f2bf(mean[11]) << 16);
            w1.z = (unsigned)f2bf(mean[12]) | ((unsigned)f2bf(mean[13]) << 16);
            w1.w = (unsigned)f2bf(mean[14]) | ((unsigned)f2bf(mean[15]) << 16);
            uint4* q = (uint4*)&eap[(size_t)kend * DE];
            q[0] = w0; q[1] = w1;
        }
        uint2 xlr = *(const uint2*)&xlb[(size_t)d * C + c0];
        float xlv[4] = {bflo(xlr.x), bfhi(xlr.x), bflo(xlr.y), bfhi(xlr.y)};
        float m[4];
#pragma unroll
        for (int i = 0; i < 4; ++i) {
            float mv = xlv[i] + xrv[i];
#pragma unroll
            for (int j = 0; j < DE; ++j) mv = fmaf(mean[j], wreg[j][i], mv);
            m[i] = mv;
        }
        float p = 0.f;
#pragma unroll
        for (int i = 0; i < 4; ++i) {
            float tt = fmaxf(m[i], NEGS * m[i]);
            p = fmaf(tt, attv[i], p);
        }
        p += __shfl_xor(p, 1);
        p += __shfl_xor(p, 2);
        p += __shfl_xor(p, 4);
        p += __shfl_xor(p, 8);
        float pe = (g == 0) ? __expf(p) : 0.f;   // count once across groups
        l_run += pe;
#pragma unroll
        for (int i = 0; i < 4; ++i) n_run[i] = fmaf(pe, xlv[i], n_run[i]);
    }

    // cross-group reduction
    l_run += __shfl_xor(l_run, 16);
    l_run += __shfl_xor(l_run, 32);
#pragma unroll
    for (int i = 0; i < 4; ++i) {
        n_run[i] += __shfl_xor(n_run[i], 16);
        n_run[i] += __shfl_xor(n_run[i], 32);
    }
    if (g == 0) {
        float4 bv = *(const float4*)&bias[c0];
        float bvv[4] = {bv.x, bv.y, bv.z, bv.w};
        float res[4];
#pragma unroll
        for (int i = 0; i < 4; ++i) {
            float v = n_run[i] / l_run + bvv[i];
            if (DO_ELU) v = (v > 0.f) ? v : (__expf(v) - 1.0f);
            res[i] = v;
        }
        if (OUT_BF16) {
            uint2 pk;
            pk.x = (unsigned)f2bf(res[0]) | ((unsigned)f2bf(res[1]) << 16);
            pk.y = (unsigned)f2bf(res[2]) | ((unsigned)f2bf(res[3]) << 16);
            *(uint2*)&((ushort*)o_)[(size_t)d * C + c0] = pk;
        } else {
            float4 pk = {res[0], res[1], res[2], res[3]};
            *(float4*)&((float*)o_)[(size_t)d * C + c0] = pk;
        }
    }
}

// ---- MFMA edge classifier: 128 edges/block, 8 waves ----
// wave w: edge-half eh=w>>2 (64 edges), n-cols nh=w&3 (64 of 256 hid)
__global__ __launch_bounds__(512, 6) void k_cls_mfma(
        const int* __restrict__ src, const int* __restrict__ dst,
        const float* __restrict__ eattr, const short* __restrict__ h2b,
        const short* __restrict__ Cw1T, const float* __restrict__ Cb1,
        const float* __restrict__ Cw2, const float* __restrict__ Cb2,
        float* __restrict__ out) {
    __shared__ short sEF[128 * LDA];
    __shared__ float sOut[128];
    int t = threadIdx.x;
    int ebase = blockIdx.x * 128;
    {
        int el = t & 127, part = t >> 7;
        int e = ebase + el;
        short8* q = (short8*)&sEF[el * LDA];
        if (part == 0) {
            const short8* p = (const short8*)&h2b[(size_t)src[e] * C];
#pragma unroll
            for (int i = 0; i < 8; ++i) q[i] = p[i];
        } else if (part == 1) {
            const short8* p = (const short8*)&h2b[(size_t)dst[e] * C];
#pragma unroll
            for (int i = 0; i < 8; ++i) q[8 + i] = p[i];
        } else if (part == 2) {
            const float4* p4 = (const float4*)&eattr[(size_t)e * DE];
            float4 c0 = p4[0], c1 = p4[1], c2 = p4[2], c3 = p4[3];
            short8 r0, r1;
            r0[0]=f2bf(c0.x); r0[1]=f2bf(c0.y); r0[2]=f2bf(c0.z); r0[3]=f2bf(c0.w);
            r0[4]=f2bf(c1.x); r0[5]=f2bf(c1.y); r0[6]=f2bf(c1.z); r0[7]=f2bf(c1.w);
            r1[0]=f2bf(c2.x); r1[1]=f2bf(c2.y); r1[2]=f2bf(c2.z); r1[3]=f2bf(c2.w);
            r1[4]=f2bf(c3.x); r1[5]=f2bf(c3.y); r1[6]=f2bf(c3.z); r1[7]=f2bf(c3.w);
            q[16] = r0; q[17] = r1;
        } else {
            short8 z = {0,0,0,0,0,0,0,0};
            q[18] = z; q[19] = z;
            sOut[el] = 0.f;
        }
    }
    __syncthreads();

    int lane = t & 63, wave = t >> 6;
    int eh = wave >> 2, nh = wave & 3;
    int l15 = lane & 15, quad = lane >> 4;
    f32x4 acc[4][4];
#pragma unroll
    for (int mt = 0; mt < 4; ++mt)
#pragma unroll
        for (int nt = 0; nt < 4; ++nt) {
            f32x4 z = {0.f, 0.f, 0.f, 0.f};
            acc[mt][nt] = z;
        }

    const short8* Bp = (const short8*)Cw1T;
#pragma unroll
    for (int kk = 0; kk < 5; ++kk) {
        short8 a[4], b[4];
#pragma unroll
        for (int mt = 0; mt < 4; ++mt)
            a[mt] = *(const short8*)&sEF[(eh * 64 + mt * 16 + l15) * LDA + kk * 32 + quad * 8];
#pragma unroll
        for (int nt = 0; nt < 4; ++nt)
            b[nt] = Bp[(nh * 64 + nt * 16 + l15) * 20 + kk * 4 + quad];
#pragma unroll
        for (int mt = 0; mt < 4; ++mt)
#pragma unroll
            for (int nt = 0; nt < 4; ++nt)
                acc[mt][nt] = __builtin_amdgcn_mfma_f32_16x16x32_bf16(
                    a[mt], b[nt], acc[mt][nt], 0, 0, 0);
    }

    float cb1v[4], cw2v[4];
#pragma unroll
    for (int nt = 0; nt < 4; ++nt) {
        int n = nh * 64 + nt * 16 + l15;
        cb1v[nt] = Cb1[n];
        cw2v[nt] = Cw2[n];
    }
    float cb2 = Cb2[0];
#pragma unroll
    for (int mt = 0; mt < 4; ++mt) {
        float p[4] = {0.f, 0.f, 0.f, 0.f};
#pragma unroll
        for (int nt = 0; nt < 4; ++nt)
#pragma unroll
            for (int r = 0; r < 4; ++r) {
                float h = acc[mt][nt][r] + cb1v[nt];
                h = (h > 0.f) ? h : (__expf(h) - 1.0f);   // fast elu
                p[r] = fmaf(h, cw2v[nt], p[r]);
            }
#pragma unroll
        for (int r = 0; r < 4; ++r) {
#pragma unroll
            for (int off = 1; off < 16; off <<= 1)
                p[r] += __shfl_xor(p[r], off);
            if (l15 == 0) atomicAdd(&sOut[eh * 64 + mt * 16 + quad * 4 + r], p[r]);
        }
    }
    __syncthreads();
    if (t < 128) out[ebase + t] = sOut[t] + cb2;
}

extern "C" void kernel_launch(void* const* d_in, const int* in_sizes, int n_in,
                              void* d_out, int out_size, void* d_ws, size_t ws_size,
                              hipStream_t stream) {
    const float* x     = (const float*)d_in[0];
    const float* eattr = (const float*)d_in[1];
    const float* W1l   = (const float*)d_in[2];
    const float* b1l   = (const float*)d_in[3];
    const float* W1r   = (const float*)d_in[4];
    const float* b1r   = (const float*)d_in[5];
    const float* We1   = (const float*)d_in[6];
    const float* att1  = (const float*)d_in[7];
    const float* bias1 = (const float*)d_in[8];
    const float* W2l   = (const float*)d_in[9];
    const float* b2l   = (const float*)d_in[10];
    const float* W2r   = (const float*)d_in[11];
    const float* b2r   = (const float*)d_in[12];
    const float* We2   = (const float*)d_in[13];
    const float* att2  = (const float*)d_in[14];
    const float* bias2 = (const float*)d_in[15];
    // d_in[16..19] (Aw1,Ab1,Aw2,Ab2) dead: softmax over size-1 axis == 1.0
    const float* Cw1   = (const float*)d_in[20];
    const float* Cb1   = (const float*)d_in[21];
    const float* Cw2   = (const float*)d_in[22];
    const float* Cb2   = (const float*)d_in[23];
    const int*   eidx  = (const int*)d_in[24];
    const int* src = eidx;
    const int* dst = eidx + NE;
    float* out = (float*)d_out;

    // workspace layout
    int*    deg      = (int*)d_ws;                     // NN
    int*    cursor   = deg + NN;                       // NN
    int*    rowptr   = cursor + NN;                    // NN+4
    int*    bsum     = rowptr + NN + 4;                // 256
    int*    boff     = bsum + 256;                     // 256 (unused, kept for layout)
    int*    src_perm = boff + 256;                     // ESL
    ushort* eap      = (ushort*)(src_perm + ESL);      // ESL*16 bf16 (CSR-ordered)
    ushort* xlb      = eap + (size_t)ESL * DE;         // 64NN bf16
    float*  xr       = (float*)(xlb + (size_t)NN * C); // 64NN
    float*  o1       = xr + (size_t)64 * NN;           // 64NN
    short*  h2b      = (short*)(o1 + (size_t)64 * NN); // 64NN bf16
    short*  cw1t     = h2b + (size_t)NN * C;           // 256*160 bf16

    // zero deg + cursor (contiguous)
    hipMemsetAsync(deg, 0, (size_t)(2 * NN) * sizeof(int), stream);

    // CSR build
    k_deg<<<(NE + 255) / 256, 256, 0, stream>>>(dst, deg);
    k_scan1<<<NBLK, 256, 0, stream>>>(deg, rowptr, bsum);
    k_scan23<<<NBLK, 256, 0, stream>>>(bsum, rowptr);

    // fused: scatter (+self slots) | lin layer 1 | Cw1 transpose/convert
    k_fused<<<SCAT_B + LIN1_B + CVT_B, 256, 0, stream>>>(
        src, dst, eattr, rowptr, cursor, src_perm, eap,
        x, W1l, b1l, W1r, b1r, xlb, xr, Cw1, cw1t);

    // ---- GAT layer 1 (inline self-loop mean; writes mean into self slot) ----
    k_gat<1, 0, 1><<<NN, 64, 0, stream>>>(src_perm, rowptr, eap, xlb, xr,
                                          We1, att1, bias1, o1);   // -> h (elu, fp32)

    // ---- GAT layer 2 (h2 written directly as bf16) ----
    k_lin<C><<<NN / 16, 256, 0, stream>>>(o1, W2l, b2l, W2r, b2r, xlb, xr);
    k_gat<0, 1, 0><<<NN, 64, 0, stream>>>(src_perm, rowptr, eap, xlb, xr,
                                          We2, att2, bias2, h2b);  // -> h2 bf16

    // ---- MFMA edge classifier on original edges ----
    k_cls_mfma<<<NE / 128, 512, 0, stream>>>(src, dst, eattr, h2b, cw1t,
                                             Cb1, Cw2, Cb2, out);
}

// Round 8
// 733.916 us; speedup vs baseline: 1.4342x; 1.4342x over previous
//
#include <hip/hip_runtime.h>
#include <math.h>

#define NN   50000
#define NE   800000
#define ESL  (NE + NN)     // CSR slots incl. one self-loop per node
#define DIN1 128
#define DE   16
#define C    64
#define HID  256
#define DCLS 144
#define KP   160      // DCLS padded to multiple of 32
#define LDA  168      // LDS row stride (bf16 elems), multiple of 8 for 16B align
#define NEGS 0.2f
#define NBLK ((NN + 255) / 256)   // 196 scan blocks

// fused kernel block ranges
#define SCAT_B ((NE + NN + 255) / 256)   // 3321
#define LIN1_B (NN / 16)                 // 3125 (16 nodes/block, 256 thr)
#define CVT_B  ((HID * KP) / 256)        // 160

typedef __attribute__((ext_vector_type(8))) short  short8;   // 8 bf16 in 4 VGPRs
typedef __attribute__((ext_vector_type(4))) float  f32x4;

// float -> bf16 (RNE)
__device__ __forceinline__ ushort f2bf(float f) {
    unsigned u = __float_as_uint(f);
    u += 0x7fffu + ((u >> 16) & 1u);
    return (ushort)(u >> 16);
}
__device__ __forceinline__ float bf2f(ushort u) {
    return __uint_as_float(((unsigned)u) << 16);
}
// packed bf16 pair -> two floats (1 op each)
__device__ __forceinline__ float bflo(unsigned w) { return __uint_as_float(w << 16); }
__device__ __forceinline__ float bfhi(unsigned w) { return __uint_as_float(w & 0xffff0000u); }

// ---- degree histogram ----
__global__ void k_deg(const int* __restrict__ dst, int* __restrict__ deg) {
    int e = blockIdx.x * blockDim.x + threadIdx.x;
    if (e < NE) atomicAdd(&deg[dst[e]], 1);
}

// ---- scan stage 1: block-local inclusive scan of (deg+1) ----
__global__ void k_scan1(const int* __restrict__ deg, int* __restrict__ rowptr,
                        int* __restrict__ bsum) {
    __shared__ int s[256];
    int t = threadIdx.x;
    int i = blockIdx.x * 256 + t;
    int v = (i < NN) ? (deg[i] + 1) : 0;
    s[t] = v;
    __syncthreads();
    for (int off = 1; off < 256; off <<= 1) {
        int u = (t >= off) ? s[t - off] : 0;
        __syncthreads();
        s[t] += u;
        __syncthreads();
    }
    if (i < NN) rowptr[i] = s[t] - v;          // exclusive within block
    if (t == 255) bsum[blockIdx.x] = s[255];
}

// ---- scan stages 2+3 merged: every block re-scans bsum, adds its prefix ----
__global__ void k_scan23(const int* __restrict__ bsum, int* __restrict__ rowptr) {
    __shared__ int s[256];
    int t = threadIdx.x;
    int v = (t < NBLK) ? bsum[t] : 0;
    s[t] = v;
    __syncthreads();
    for (int off = 1; off < 256; off <<= 1) {
        int u = (t >= off) ? s[t - off] : 0;
        __syncthreads();
        s[t] += u;
        __syncthreads();
    }
    int add = (blockIdx.x > 0) ? s[blockIdx.x - 1] : 0;
    int i = blockIdx.x * 256 + t;
    if (i < NN) rowptr[i] += add;
    if (i == 0) rowptr[NN] = ESL;
}

// ---- lin body: 256 threads cover 16 nodes (two 128-thread halves of 8) ----
template<int DINT>
__device__ __forceinline__ void lin_body(
        int lb, int t, const float* __restrict__ x,
        const float* __restrict__ Wl, const float* __restrict__ bl,
        const float* __restrict__ Wr, const float* __restrict__ br,
        ushort* __restrict__ xlb, float* __restrict__ xr) {
    int i0 = lb * 16 + (t >> 7) * 8;
    int tt = t & 127;
    int c = tt & 63;
    bool isl = tt < 64;
    const float* W = isl ? Wl : Wr;
    float bb = isl ? bl[c] : br[c];
    float acc[8];
#pragma unroll
    for (int n = 0; n < 8; ++n) acc[n] = bb;
    for (int k = 0; k < DINT; ++k) {
        float wk = W[k * C + c];
#pragma unroll
        for (int n = 0; n < 8; ++n)
            acc[n] = fmaf(x[(size_t)(i0 + n) * DINT + k], wk, acc[n]);
    }
    if (isl) {
#pragma unroll
        for (int n = 0; n < 8; ++n)
            xlb[(size_t)(i0 + n) * C + c] = f2bf(acc[n]);
    } else {
#pragma unroll
        for (int n = 0; n < 8; ++n)
            xr[(size_t)(i0 + n) * C + c] = acc[n];
    }
}

// ---- fused: scatter(+self slots) | lin1 | cvt_w  (independent parts) ----
__global__ void k_fused(const int* __restrict__ src, const int* __restrict__ dst,
                        const float* __restrict__ eattr,
                        const int* __restrict__ rowptr, int* __restrict__ cursor,
                        int* __restrict__ src_perm, ushort* __restrict__ eap,
                        const float* __restrict__ x,
                        const float* __restrict__ W1l, const float* __restrict__ b1l,
                        const float* __restrict__ W1r, const float* __restrict__ b1r,
                        ushort* __restrict__ xlb, float* __restrict__ xr,
                        const float* __restrict__ Cw1, short* __restrict__ Cw1T) {
    int b = blockIdx.x;
    int t = threadIdx.x;
    if (b < SCAT_B) {
        int e = b * 256 + t;
        if (e < NE) {
            int d = dst[e];
            int pos = atomicAdd(&cursor[d], 1);
            int idx = rowptr[d] + pos;
            src_perm[idx] = src[e];
            const float4* p4 = (const float4*)&eattr[(size_t)e * DE];
            float4 c0 = p4[0], c1 = p4[1], c2 = p4[2], c3 = p4[3];
            short8 r0, r1;
            r0[0]=f2bf(c0.x); r0[1]=f2bf(c0.y); r0[2]=f2bf(c0.z); r0[3]=f2bf(c0.w);
            r0[4]=f2bf(c1.x); r0[5]=f2bf(c1.y); r0[6]=f2bf(c1.z); r0[7]=f2bf(c1.w);
            r1[0]=f2bf(c2.x); r1[1]=f2bf(c2.y); r1[2]=f2bf(c2.z); r1[3]=f2bf(c2.w);
            r1[4]=f2bf(c3.x); r1[5]=f2bf(c3.y); r1[6]=f2bf(c3.z); r1[7]=f2bf(c3.w);
            short8* q = (short8*)&eap[(size_t)idx * DE];
            q[0] = r0; q[1] = r1;
        } else if (e < NE + NN) {
            int n = e - NE;
            src_perm[rowptr[n + 1] - 1] = n;   // self slot
        }
    } else if (b < SCAT_B + LIN1_B) {
        lin_body<DIN1>(b - SCAT_B, t, x, W1l, b1l, W1r, b1r, xlb, xr);
    } else {
        int idx = (b - SCAT_B - LIN1_B) * 256 + t;   // < 40960
        int n = idx / KP, k = idx - n * KP;
        Cw1T[n * KP + k] = (k < DCLS) ? (short)f2bf(Cw1[k * HID + n]) : (short)0;
    }
}

// ---- standalone lin (layer 2) ----
template<int DINT>
__global__ void k_lin(const float* __restrict__ x,
                      const float* __restrict__ Wl, const float* __restrict__ bl,
                      const float* __restrict__ Wr, const float* __restrict__ br,
                      ushort* __restrict__ xlb, float* __restrict__ xr) {
    lin_body<DINT>(blockIdx.x, threadIdx.x, x, Wl, bl, Wr, br, xlb, xr);
}

// ---- fused GAT layer, 4-edge x 16-lane layout, src prefetch ----
template<int DO_ELU, int OUT_BF16, int SELF_INLINE>
__global__ __launch_bounds__(64, 3) void k_gat(
        const int* __restrict__ src_perm, const int* __restrict__ rowptr,
        ushort* __restrict__ eap,
        const ushort* __restrict__ xlb, const float* __restrict__ xr,
        const float* __restrict__ We, const float* __restrict__ att,
        const float* __restrict__ bias, void* __restrict__ o_) {
    int d = blockIdx.x;
    int lane = threadIdx.x;
    int g = lane >> 4, l = lane & 15;
    int c0 = l * 4;
    float wreg[DE][4];
#pragma unroll
    for (int j = 0; j < DE; ++j) {
        float4 wv = *(const float4*)&We[j * C + c0];
        wreg[j][0] = wv.x; wreg[j][1] = wv.y; wreg[j][2] = wv.z; wreg[j][3] = wv.w;
    }
    float4 av4 = *(const float4*)&att[c0];
    float attv[4] = {av4.x, av4.y, av4.z, av4.w};
    float4 xr4 = *(const float4*)&xr[(size_t)d * C + c0];
    float xrv[4] = {xr4.x, xr4.y, xr4.z, xr4.w};

    float l_run = 0.f, n_run[4] = {0.f, 0.f, 0.f, 0.f};
    float easum[DE];
    if (SELF_INLINE) {
#pragma unroll
        for (int j = 0; j < DE; ++j) easum[j] = 0.f;
    }
    int kb = rowptr[d], ke = rowptr[d + 1];
    int kend = SELF_INLINE ? (ke - 1) : ke;

    if (kend > kb) {
        int kk0 = kb + g;
        int s_cur = src_perm[(kk0 < kend) ? kk0 : kb];
        for (int k = kb; k < kend; k += 4) {
            int kk = k + g;
            bool valid = kk < kend;
            int kidx = valid ? kk : kb;
            int kkn = kk + 4;
            int s_nxt = src_perm[(kkn < kend) ? kkn : kb];
            float validf = valid ? 1.f : 0.f;
            uint2 xlr = *(const uint2*)&xlb[(size_t)s_cur * C + c0];
            float xlv[4] = {bflo(xlr.x), bfhi(xlr.x), bflo(xlr.y), bfhi(xlr.y)};
            const uint4* ep = (const uint4*)&eap[(size_t)kidx * DE];
            uint4 e0 = ep[0], e1 = ep[1];
            float m[4];
#pragma unroll
            for (int i = 0; i < 4; ++i) m[i] = xlv[i] + xrv[i];
            unsigned ew[8] = {e0.x, e0.y, e0.z, e0.w, e1.x, e1.y, e1.z, e1.w};
#pragma unroll
            for (int wji = 0; wji < 8; ++wji) {
                float elo = bflo(ew[wji]), ehi = bfhi(ew[wji]);
#pragma unroll
                for (int i = 0; i < 4; ++i) {
                    m[i] = fmaf(elo, wreg[2 * wji][i], m[i]);
                    m[i] = fmaf(ehi, wreg[2 * wji + 1][i], m[i]);
                }
                if (SELF_INLINE) {
                    easum[2 * wji]     = fmaf(validf, elo, easum[2 * wji]);
                    easum[2 * wji + 1] = fmaf(validf, ehi, easum[2 * wji + 1]);
                }
            }
            float p = 0.f;
#pragma unroll
            for (int i = 0; i < 4; ++i) {
                float tt = fmaxf(m[i], NEGS * m[i]);   // leaky_relu
                p = fmaf(tt, attv[i], p);
            }
            p += __shfl_xor(p, 1);
            p += __shfl_xor(p, 2);
            p += __shfl_xor(p, 4);
            p += __shfl_xor(p, 8);
            float pe = valid ? __expf(p) : 0.f;
            l_run += pe;
#pragma unroll
            for (int i = 0; i < 4; ++i) n_run[i] = fmaf(pe, xlv[i], n_run[i]);
            s_cur = s_nxt;
        }
    }

    if (SELF_INLINE) {
#pragma unroll
        for (int j = 0; j < DE; ++j) {
            easum[j] += __shfl_xor(easum[j], 16);
            easum[j] += __shfl_xor(easum[j], 32);
        }
        float rdeg = 1.f / fmaxf((float)(kend - kb), 1.f);
        float mean[DE];
#pragma unroll
        for (int j = 0; j < DE; ++j) mean[j] = easum[j] * rdeg;
        if (lane == 0) {
            uint4 w0, w1;
            w0.x = (unsigned)f2bf(mean[0])  | ((unsigned)f2bf(mean[1])  << 16);
            w0.y = (unsigned)f2bf(mean[2])  | ((unsigned)f2bf(mean[3])  << 16);
            w0.z = (unsigned)f2bf(mean[4])  | ((unsigned)f2bf(mean[5])  << 16);
            w0.w = (unsigned)f2bf(mean[6])  | ((unsigned)f2bf(mean[7])  << 16);
            w1.x = (unsigned)f2bf(mean[8])  | ((unsigned)f2bf(mean[9])  << 16);
            w1.y = (unsigned)f2bf(mean[10]) | ((unsigned)f2bf(mean[11]) << 16);
            w1.z = (unsigned)f2bf(mean[12]) | ((unsigned)f2bf(mean[13]) << 16);
            w1.w = (unsigned)f2bf(mean[14]) | ((unsigned)f2bf(mean[15]) << 16);
            uint4* q = (uint4*)&eap[(size_t)kend * DE];
            q[0] = w0; q[1] = w1;
        }
        uint2 xlr = *(const uint2*)&xlb[(size_t)d * C + c0];
        float xlv[4] = {bflo(xlr.x), bfhi(xlr.x), bflo(xlr.y), bfhi(xlr.y)};
        float m[4];
#pragma unroll
        for (int i = 0; i < 4; ++i) {
            float mv = xlv[i] + xrv[i];
#pragma unroll
            for (int j = 0; j < DE; ++j) mv = fmaf(mean[j], wreg[j][i], mv);
            m[i] = mv;
        }
        float p = 0.f;
#pragma unroll
        for (int i = 0; i < 4; ++i) {
            float tt = fmaxf(m[i], NEGS * m[i]);
            p = fmaf(tt, attv[i], p);
        }
        p += __shfl_xor(p, 1);
        p += __shfl_xor(p, 2);
        p += __shfl_xor(p, 4);
        p += __shfl_xor(p, 8);
        float pe = (g == 0) ? __expf(p) : 0.f;
        l_run += pe;
#pragma unroll
        for (int i = 0; i < 4; ++i) n_run[i] = fmaf(pe, xlv[i], n_run[i]);
    }

    l_run += __shfl_xor(l_run, 16);
    l_run += __shfl_xor(l_run, 32);
#pragma unroll
    for (int i = 0; i < 4; ++i) {
        n_run[i] += __shfl_xor(n_run[i], 16);
        n_run[i] += __shfl_xor(n_run[i], 32);
    }
    if (g == 0) {
        float4 bv = *(const float4*)&bias[c0];
        float bvv[4] = {bv.x, bv.y, bv.z, bv.w};
        float res[4];
#pragma unroll
        for (int i = 0; i < 4; ++i) {
            float v = n_run[i] / l_run + bvv[i];
            if (DO_ELU) v = (v > 0.f) ? v : (__expf(v) - 1.0f);
            res[i] = v;
        }
        if (OUT_BF16) {
            uint2 pk;
            pk.x = (unsigned)f2bf(res[0]) | ((unsigned)f2bf(res[1]) << 16);
            pk.y = (unsigned)f2bf(res[2]) | ((unsigned)f2bf(res[3]) << 16);
            *(uint2*)&((ushort*)o_)[(size_t)d * C + c0] = pk;
        } else {
            float4 pk = {res[0], res[1], res[2], res[3]};
            *(float4*)&((float*)o_)[(size_t)d * C + c0] = pk;
        }
    }
}

// ---- MFMA edge classifier: 64 edges/block, 4 waves, OPERAND-SWAPPED ----
// A = Cw1T rows (M = hid, wave w owns hid w*64..w*64+63), B = EF tile
// (N = edge). D[m=hid][n=edge]: col(lane&15)=edge, row(quad*4+r)=hid.
// Cw2-dot reduces over hid -> in-thread (16 vals) + 2 cross-quad shuffles.
// Both A and B are row-major over k, so fragment reads are identical to the
// unswapped version; only MFMA arg order + epilogue indexing differ.
__global__ __launch_bounds__(256, 4) void k_cls_mfma(
        const int* __restrict__ src, const int* __restrict__ dst,
        const float* __restrict__ eattr, const short* __restrict__ h2b,
        const short* __restrict__ Cw1T, const float* __restrict__ Cb1,
        const float* __restrict__ Cw2, const float* __restrict__ Cb2,
        float* __restrict__ out) {
    __shared__ short sEF[64 * LDA];
    __shared__ float sOut[64];
    int t = threadIdx.x;
    int ebase = blockIdx.x * 64;
    {
        int el = t & 63, part = t >> 6;
        int e = ebase + el;
        short8* q = (short8*)&sEF[el * LDA];
        if (part == 0) {
            const short8* p = (const short8*)&h2b[(size_t)src[e] * C];
#pragma unroll
            for (int i = 0; i < 8; ++i) q[i] = p[i];
        } else if (part == 1) {
            const short8* p = (const short8*)&h2b[(size_t)dst[e] * C];
#pragma unroll
            for (int i = 0; i < 8; ++i) q[8 + i] = p[i];
        } else if (part == 2) {
            const float4* p4 = (const float4*)&eattr[(size_t)e * DE];
            float4 c0 = p4[0], c1 = p4[1], c2 = p4[2], c3 = p4[3];
            short8 r0, r1;
            r0[0]=f2bf(c0.x); r0[1]=f2bf(c0.y); r0[2]=f2bf(c0.z); r0[3]=f2bf(c0.w);
            r0[4]=f2bf(c1.x); r0[5]=f2bf(c1.y); r0[6]=f2bf(c1.z); r0[7]=f2bf(c1.w);
            r1[0]=f2bf(c2.x); r1[1]=f2bf(c2.y); r1[2]=f2bf(c2.z); r1[3]=f2bf(c2.w);
            r1[4]=f2bf(c3.x); r1[5]=f2bf(c3.y); r1[6]=f2bf(c3.z); r1[7]=f2bf(c3.w);
            q[16] = r0; q[17] = r1;
        } else {
            short8 z = {0,0,0,0,0,0,0,0};
            q[18] = z; q[19] = z;
            sOut[el] = 0.f;
        }
    }
    __syncthreads();

    int lane = t & 63, wave = t >> 6;     // wave = hid quarter
    int l15 = lane & 15, quad = lane >> 4;
    f32x4 acc[4][4];                      // [mt (hid)][nt (edge)]
#pragma unroll
    for (int mt = 0; mt < 4; ++mt)
#pragma unroll
        for (int nt = 0; nt < 4; ++nt) {
            f32x4 z = {0.f, 0.f, 0.f, 0.f};
            acc[mt][nt] = z;
        }

    const short8* Bp = (const short8*)Cw1T;
#pragma unroll
    for (int kk = 0; kk < 5; ++kk) {
        short8 a[4], b[4];
#pragma unroll
        for (int mt = 0; mt < 4; ++mt)                     // A: Cw1T row = hid
            a[mt] = Bp[(wave * 64 + mt * 16 + l15) * 20 + kk * 4 + quad];
#pragma unroll
        for (int nt = 0; nt < 4; ++nt)                     // B: EF row = edge
            b[nt] = *(const short8*)&sEF[(nt * 16 + l15) * LDA + kk * 32 + quad * 8];
#pragma unroll
        for (int mt = 0; mt < 4; ++mt)
#pragma unroll
            for (int nt = 0; nt < 4; ++nt)
                acc[mt][nt] = __builtin_amdgcn_mfma_f32_16x16x32_bf16(
                    a[mt], b[nt], acc[mt][nt], 0, 0, 0);
    }

    // epilogue: lane holds edge = nt*16+l15, hid = wave*64 + mt*16 + quad*4 + r
    float pacc[4] = {0.f, 0.f, 0.f, 0.f};
#pragma unroll
    for (int mt = 0; mt < 4; ++mt) {
        int hb = wave * 64 + mt * 16 + quad * 4;
        float4 cb4 = *(const float4*)&Cb1[hb];
        float4 cw4 = *(const float4*)&Cw2[hb];
        float cbv[4] = {cb4.x, cb4.y, cb4.z, cb4.w};
        float cwv[4] = {cw4.x, cw4.y, cw4.z, cw4.w};
#pragma unroll
        for (int nt = 0; nt < 4; ++nt)
#pragma unroll
            for (int r = 0; r < 4; ++r) {
                float h = acc[mt][nt][r] + cbv[r];
                h = (h > 0.f) ? h : (__expf(h) - 1.0f);   // fast elu
                pacc[nt] = fmaf(h, cwv[r], pacc[nt]);
            }
    }
#pragma unroll
    for (int nt = 0; nt < 4; ++nt) {
        float p = pacc[nt];
        p += __shfl_xor(p, 16);    // sum over quads (hid within wave)
        p += __shfl_xor(p, 32);
        if (quad == 0) atomicAdd(&sOut[nt * 16 + l15], p);
    }
    __syncthreads();
    float cb2 = Cb2[0];
    if (t < 64) out[ebase + t] = sOut[t] + cb2;
}

extern "C" void kernel_launch(void* const* d_in, const int* in_sizes, int n_in,
                              void* d_out, int out_size, void* d_ws, size_t ws_size,
                              hipStream_t stream) {
    const float* x     = (const float*)d_in[0];
    const float* eattr = (const float*)d_in[1];
    const float* W1l   = (const float*)d_in[2];
    const float* b1l   = (const float*)d_in[3];
    const float* W1r   = (const float*)d_in[4];
    const float* b1r   = (const float*)d_in[5];
    const float* We1   = (const float*)d_in[6];
    const float* att1  = (const float*)d_in[7];
    const float* bias1 = (const float*)d_in[8];
    const float* W2l   = (const float*)d_in[9];
    const float* b2l   = (const float*)d_in[10];
    const float* W2r   = (const float*)d_in[11];
    const float* b2r   = (const float*)d_in[12];
    const float* We2   = (const float*)d_in[13];
    const float* att2  = (const float*)d_in[14];
    const float* bias2 = (const float*)d_in[15];
    // d_in[16..19] (Aw1,Ab1,Aw2,Ab2) dead: softmax over size-1 axis == 1.0
    const float* Cw1   = (const float*)d_in[20];
    const float* Cb1   = (const float*)d_in[21];
    const float* Cw2   = (const float*)d_in[22];
    const float* Cb2   = (const float*)d_in[23];
    const int*   eidx  = (const int*)d_in[24];
    const int* src = eidx;
    const int* dst = eidx + NE;
    float* out = (float*)d_out;

    // workspace layout
    int*    deg      = (int*)d_ws;                     // NN
    int*    cursor   = deg + NN;                       // NN
    int*    rowptr   = cursor + NN;                    // NN+4
    int*    bsum     = rowptr + NN + 4;                // 256
    int*    boff     = bsum + 256;                     // 256 (unused, kept for layout)
    int*    src_perm = boff + 256;                     // ESL
    ushort* eap      = (ushort*)(src_perm + ESL);      // ESL*16 bf16 (CSR-ordered)
    ushort* xlb      = eap + (size_t)ESL * DE;         // 64NN bf16
    float*  xr       = (float*)(xlb + (size_t)NN * C); // 64NN
    float*  o1       = xr + (size_t)64 * NN;           // 64NN
    short*  h2b      = (short*)(o1 + (size_t)64 * NN); // 64NN bf16
    short*  cw1t     = h2b + (size_t)NN * C;           // 256*160 bf16

    // zero deg + cursor (contiguous)
    hipMemsetAsync(deg, 0, (size_t)(2 * NN) * sizeof(int), stream);

    // CSR build
    k_deg<<<(NE + 255) / 256, 256, 0, stream>>>(dst, deg);
    k_scan1<<<NBLK, 256, 0, stream>>>(deg, rowptr, bsum);
    k_scan23<<<NBLK, 256, 0, stream>>>(bsum, rowptr);

    // fused: scatter (+self slots) | lin layer 1 | Cw1 transpose/convert
    k_fused<<<SCAT_B + LIN1_B + CVT_B, 256, 0, stream>>>(
        src, dst, eattr, rowptr, cursor, src_perm, eap,
        x, W1l, b1l, W1r, b1r, xlb, xr, Cw1, cw1t);

    // ---- GAT layer 1 (inline self-loop mean; writes mean into self slot) ----
    k_gat<1, 0, 1><<<NN, 64, 0, stream>>>(src_perm, rowptr, eap, xlb, xr,
                                          We1, att1, bias1, o1);   // -> h (elu, fp32)

    // ---- GAT layer 2 (h2 written directly as bf16) ----
    k_lin<C><<<NN / 16, 256, 0, stream>>>(o1, W2l, b2l, W2r, b2r, xlb, xr);
    k_gat<0, 1, 0><<<NN, 64, 0, stream>>>(src_perm, rowptr, eap, xlb, xr,
                                          We2, att2, bias2, h2b);  // -> h2 bf16

    // ---- MFMA edge classifier on original edges ----
    k_cls_mfma<<<NE / 64, 256, 0, stream>>>(src, dst, eattr, h2b, cw1t,
                                            Cb1, Cw2, Cb2, out);
}